// Round 16
// baseline (80.078 us; speedup 1.0000x reference)
//
#include <hip/hip_runtime.h>
#include <hip/hip_bf16.h>

// Flow_6081673691683: Heun flow (10 steps x 2 MLP evals, H=256) + analytic logdet.
// logabsdet = 240*ln(0.95) exactly -> jacrev/slogdet eliminated.
// R16: PHASE-OFFSET WAVE-GROUP SPECIALIZATION. 128 blocks x 8 waves; waves
// split into 2 groups of 4, each owning an independent 8-sample tile with
// private LDS, running the 4-phase eval pipeline (L1 / L2 / L3+L4 / reduce)
// OFFSET BY 2 PHASES. Block barriers pair heavy phases with light ones on
// every SIMD -> one wave's MFMA chain fills the other's latency stalls.
// (R10 failed with same-phase tiles; R13/14 failed on cross-block reg caps;
// this keeps 2 waves/SIMD with the 256-reg budget -- R14 measured this
// 4-N-frag working set at 140 VGPRs.) fp8 L2/L3/L4, floor swizzles kept.

typedef unsigned short ushort_t;
typedef float f32x4 __attribute__((ext_vector_type(4)));
typedef short s16x8 __attribute__((ext_vector_type(8)));
typedef long f8x8;   // 8 packed fp8 (2 VGPR)

#define NB      2048
#define OBS_D   48
#define XDIM    24
#define NSTEPS  10
#define DT      0.1f
#define PP      0.95f
#define SCL     2.885390081777927f   // 2*log2(e)

// d_ws layout (BYTES) — identical to R12/R15
#define W1U  0        // W1 full bf16 frags (cinit only): 32768 B
#define W1AU 32768    // W1 act-only bf16 frags (k<12, K=32): 16384 B
#define W2F  49152    // W2 fp8 frags: 65536 B
#define W3F  114688   // W3 fp8 frags: 65536 B
#define W4F  180224   // W4 fp8 frags: 4096 B
#define FRAG_BLOCKS 624   // 624*256 == 159744 elements (mixed width)
#define LP_BLOCKS 8

// Per-GROUP LDS layout (bytes; group stride 15360, 2 groups = 30720 total)
#define G_BUFA 0        // 4096 (h1/h3 fp8: 16 rows x 256B, XOR full-ar key)
#define G_BUFB 4096     // 4096 (h2 fp8)
#define G_AIN  8192     // 1024 (16 rows x 64B bf16 act, XOR (r&3)<<4)
#define G_PART 9216     // 4096 (16 row x 16 col x 4 slot f32, slot XOR)
#define G_STG  13312    // 2048 (init staging bf16: 16 rows x 128B, XOR (r&7)<<4)
#define G_STRIDE 15360

__device__ __forceinline__ ushort_t f2bf(float f) {
  unsigned u = __builtin_bit_cast(unsigned, f);
  u += 0x7fffu + ((u >> 16) & 1u);          // RNE
  return (ushort_t)(u >> 16);
}

__device__ __forceinline__ unsigned char f2fp8(float f) {
  int p = __builtin_amdgcn_cvt_pk_fp8_f32(f, 0.f, 0, false);
  return (unsigned char)(p & 0xFF);
}

// input pre-scaled by 2*log2(e):  tanh = 1 - 2/(1 + exp2(u))
__device__ __forceinline__ float tanh_s(float u) {
  float e = __builtin_amdgcn_exp2f(u);
  return __builtin_fmaf(-2.f, __builtin_amdgcn_rcpf(1.f + e), 1.f);
}

// packed-pair byte offset within a 128B bf16 row (cols 0..63), pre-swizzle
__device__ __forceinline__ int pair_byte(int c) {
  return (((c >> 5) << 6) | ((c & 15) << 2) | (((c >> 4) & 1) << 1));
}

// ---------------------------------------------------------------------------
// Prep (identical to R12/R15): weights -> MFMA B-fragment order (permuted K)
// + analytic log_probs. k_eff = kt*32 + 4*(l>>4) + (j>>1) + 16*(j&1).
// W1/W2/W3 scaled by 2*log2(e); W4 unscaled. W2/W3/W4 fp8 e4m3.
// ---------------------------------------------------------------------------
__global__ void prep_kernel(const float* __restrict__ W1, const float* __restrict__ b1,
                            const float* __restrict__ W2, const float* __restrict__ W3,
                            const float* __restrict__ W4, const float* __restrict__ x0,
                            const int* __restrict__ jac, float* __restrict__ out,
                            unsigned char* __restrict__ ws) {
  int bid = blockIdx.x;
  int tid = threadIdx.x;
  if (bid < FRAG_BLOCKS) {
    int e = bid * 256 + tid;           // 0 .. 159743
    if (e < 16384) {                   // W1 full bf16 (61x256 + b1 row 61), scaled
      int kt = e >> 13; int r = e & 8191;
      int nt = r >> 9, l = (r >> 3) & 63, j = r & 7;
      int k = kt * 32 + ((l >> 4) << 2) + (j >> 1) + ((j & 1) << 4);
      int col = nt * 16 + (l & 15);
      float v = SCL * ((k < 61) ? W1[k * 256 + col] : ((k == 61) ? b1[col] : 0.f));
      *(ushort_t*)(ws + W1U + 2 * e) = f2bf(v);
    } else if (e < 24576) {            // W1A bf16: act rows only (k<12), K=32, scaled
      int e2 = e - 16384;
      int nt = e2 >> 9; int r = e2 & 511;
      int l = (r >> 3) & 63, j = r & 7;
      int k = ((l >> 4) << 2) + (j >> 1) + ((j & 1) << 4);
      float v = (k < 12) ? SCL * W1[k * 256 + nt * 16 + (l & 15)] : 0.f;
      *(ushort_t*)(ws + W1AU + 2 * e2) = f2bf(v);
    } else if (e < 90112) {            // W2 fp8, scaled
      int e2 = e - 24576;
      int kt = e2 >> 13; int r = e2 & 8191;
      int nt = r >> 9, l = (r >> 3) & 63, j = r & 7;
      int k = kt * 32 + ((l >> 4) << 2) + (j >> 1) + ((j & 1) << 4);
      ws[W2F + e2] = f2fp8(SCL * W2[k * 256 + nt * 16 + (l & 15)]);
    } else if (e < 155648) {           // W3 fp8, scaled
      int e2 = e - 90112;
      int kt = e2 >> 13; int r = e2 & 8191;
      int nt = r >> 9, l = (r >> 3) & 63, j = r & 7;
      int k = kt * 32 + ((l >> 4) << 2) + (j >> 1) + ((j & 1) << 4);
      ws[W3F + e2] = f2fp8(SCL * W3[k * 256 + nt * 16 + (l & 15)]);
    } else {                           // W4 fp8 (256x12 -> N pad 16), UNscaled
      int e2 = e - 155648;
      int kt = e2 >> 9; int r = e2 & 511;
      int l = (r >> 3) & 63, j = r & 7;
      int k = kt * 32 + ((l >> 4) << 2) + (j >> 1) + ((j & 1) << 4);
      int col = l & 15;
      ws[W4F + e2] = f2fp8((col < 12) ? W4[k * 12 + col] : 0.f);
    }
  } else {
    int s = (bid - FRAG_BLOCKS) * 256 + tid;   // 0..2047
    float acc = 0.f;
    #pragma unroll 4
    for (int j = 0; j < XDIM; ++j) { float v = x0[s * XDIM + j]; acc += v * v; }
    // -0.5*d*ln(2pi) = -22.054524796912143 ; -240*ln(0.95) = +12.310390653012128
    float C = (jac[0] != 0) ? -9.744134143900015f : -22.054524796912143f;
    out[NB * XDIM + s] = -0.5f * acc + C;
  }
}

// ---------------------------------------------------------------------------
// Main: 128 blocks x 512 threads. Group grp = wv>>2 owns 8 samples
// (rows row0+8*grp .. +7) with waves lw = wv&3 covering 64 cols each.
// Group B runs 2 phases behind group A through shared barriers.
// ---------------------------------------------------------------------------
__global__ __launch_bounds__(512, 2) void flow_main(
    const float* __restrict__ obs, const float* __restrict__ x0,
    const float* __restrict__ W1g, const float* __restrict__ b2g,
    const float* __restrict__ b3g, const float* __restrict__ b4g,
    const unsigned char* __restrict__ ws, float* __restrict__ out) {
  __shared__ char lds[2 * G_STRIDE];
  const int tid  = threadIdx.x;
  const int lane = tid & 63;
  const int wv   = tid >> 6;
  const int grp  = wv >> 2;         // 0 or 1
  const int lw   = wv & 3;          // wave within group
  const int g    = lane >> 4;
  const int ar   = lane & 15;
  const int gtid = tid & 255;
  const int rs   = gtid >> 4, cs = gtid & 15;   // reduce role within group
  const int row0 = blockIdx.x * 16 + grp * 8;   // group's first sample
  const int gb   = grp * G_STRIDE;
  const int sw   = (ar & 7) << 4;               // bf16 swizzle (STG)

  // staggered fp8 read offsets (group-relative): roff[c] -> seg (2lw+c)&7
  int roff[8];
  #pragma unroll
  for (int c = 0; c < 8; ++c)
    roff[c] = ar * 256 + (((((2 * lw + c) & 7) * 32) + g * 8) ^ (ar << 3));
  // h-writes: pair A -> seg 2lw, pair B -> seg 2lw+1; PART slot XOR
  int woffA[4], woffB[4], pwoff[4];
  #pragma unroll
  for (int r = 0; r < 4; ++r) {
    int rw = 4 * g + r;
    woffA[r] = rw * 256 + (((2 * lw) * 32 + ar * 2) ^ (rw << 3));
    woffB[r] = rw * 256 + (((2 * lw + 1) * 32 + ar * 2) ^ (rw << 3));
    int slot = lw ^ ((ar >> 2) & 3) ^ g;        // bijective in lw per (row,col)
    pwoff[r] = G_PART + ((rw * 64 + ar * 4 + slot) << 2);
  }

  // --- zero group STG (512 dw) and AIN (256 dw) ---
  ((unsigned*)(lds + gb + G_STG))[gtid]       = 0u;
  ((unsigned*)(lds + gb + G_STG))[gtid + 256] = 0u;
  ((unsigned*)(lds + gb + G_AIN))[gtid]       = 0u;
  __syncthreads();

  // --- fill STG = [0(act)|obs|0(t)|1(bias)], rows 0..7 real ---
  for (int idx = gtid; idx < 8 * OBS_D; idx += 256) {
    int r = idx / OBS_D, o = idx - r * OBS_D;
    int byt = pair_byte(12 + o) ^ ((r & 7) << 4);
    *(ushort_t*)(lds + gb + G_STG + r * 128 + byt) = f2bf(obs[(row0 + r) * OBS_D + o]);
  }
  if (gtid < 16)   // col 61 = 1.0 -> b1 (scaled b1 lives in W1 frag row 61)
    *(ushort_t*)(lds + gb + G_STG + gtid * 128 + (pair_byte(61) ^ ((gtid & 7) << 4))) =
        (ushort_t)0x3F80;

  // --- act seed (y0) into AIN + z/y state regs (group reduce roles) ---
  float zr = 0.f, yr = 0.f, zir = 0.f;
  if (rs < 8 && cs < 12) {
    zr = x0[(row0 + rs) * XDIM + cs];
    yr = x0[(row0 + rs) * XDIM + 12 + cs];
    *(ushort_t*)(lds + gb + G_AIN + rs * 64 + ((cs * 4) ^ ((rs & 3) << 4))) = f2bf(yr);
  }

  // --- weight fragments: wave's 4 N-frags (nf = 4lw+n), staggered kt ---
  s16x8 w1o[2][4], w1a[4];
  f8x8 w2f[8][4], w3f[8][4], w4f[2];
  #pragma unroll
  for (int kt = 0; kt < 2; ++kt)
    #pragma unroll
    for (int n = 0; n < 4; ++n)
      w1o[kt][n] = *(const s16x8*)(ws + W1U + (((kt * 16) + (4 * lw + n)) * 64 + lane) * 16);
  #pragma unroll
  for (int n = 0; n < 4; ++n)
    w1a[n] = *(const s16x8*)(ws + W1AU + ((4 * lw + n) * 64 + lane) * 16);
  #pragma unroll
  for (int c = 0; c < 8; ++c) {
    int kt = (2 * lw + c) & 7;
    #pragma unroll
    for (int n = 0; n < 4; ++n) {
      w2f[c][n] = *(const f8x8*)(ws + W2F + (((kt * 16) + (4 * lw + n)) * 64 + lane) * 8);
      w3f[c][n] = *(const f8x8*)(ws + W3F + (((kt * 16) + (4 * lw + n)) * 64 + lane) * 8);
    }
  }
  #pragma unroll
  for (int s = 0; s < 2; ++s)
    w4f[s] = *(const f8x8*)(ws + W4F + (((2 * lw + s) * 64) + lane) * 8);
  #pragma unroll
  for (int n = 0; n < 4; ++n) asm volatile("" : "+v"(w1a[n]));
  asm volatile("" : "+v"(w4f[0]), "+v"(w4f[1]));
  #pragma unroll
  for (int c = 0; c < 8; ++c)
    asm volatile("" : "+v"(w2f[c][0]), "+v"(w2f[c][1]), "+v"(w2f[c][2]), "+v"(w2f[c][3]),
                     "+v"(w3f[c][0]), "+v"(w3f[c][1]), "+v"(w3f[c][2]), "+v"(w3f[c][3]));

  // t-row of W1 + biases (scaled)
  float w1t[4], b2s[4], b3s[4];
  #pragma unroll
  for (int n = 0; n < 4; ++n) {
    w1t[n] = SCL * W1g[60 * 256 + (4 * lw + n) * 16 + ar];
    b2s[n] = SCL * b2g[(4 * lw + n) * 16 + ar];
    b3s[n] = SCL * b3g[(4 * lw + n) * 16 + ar];
  }
  const float b4v = (cs < 12) ? b4g[cs] : 0.f;

  __syncthreads();

  // --- cinit[n] = ([0|obs|0|1] @ W1s): step-invariant L1 pre-activation ---
  const f32x4 z4 = {0.f, 0.f, 0.f, 0.f};
  f32x4 ci[4] = {z4, z4, z4, z4};
  #pragma unroll
  for (int kt = 0; kt < 2; ++kt) {
    s16x8 a = *(const s16x8*)(lds + gb + G_STG + ar * 128 + ((kt * 64 + g * 16) ^ sw));
    #pragma unroll
    for (int n = 0; n < 4; ++n)
      ci[n] = __builtin_amdgcn_mfma_f32_16x16x32_bf16(a, w1o[kt][n], ci[n], 0, 0, 0);
  }

  // ---- phase bodies ----
  auto L1 = [&](int stepi) {
    float t = (float)stepi * DT;
    f32x4 acc[4];
    #pragma unroll
    for (int n = 0; n < 4; ++n) {
      float tn = t * w1t[n];
      acc[n] = ci[n];
      #pragma unroll
      for (int r = 0; r < 4; ++r) acc[n][r] += tn;
    }
    s16x8 a = *(const s16x8*)(lds + gb + G_AIN + ar * 64 + ((g * 16) ^ ((ar & 3) << 4)));
    #pragma unroll
    for (int n = 0; n < 4; ++n)
      acc[n] = __builtin_amdgcn_mfma_f32_16x16x32_bf16(a, w1a[n], acc[n], 0, 0, 0);
    #pragma unroll
    for (int r = 0; r < 4; ++r) {
      unsigned pA = (unsigned)__builtin_amdgcn_cvt_pk_fp8_f32(
          tanh_s(acc[0][r]), tanh_s(acc[1][r]), 0, false);
      unsigned pB = (unsigned)__builtin_amdgcn_cvt_pk_fp8_f32(
          tanh_s(acc[2][r]), tanh_s(acc[3][r]), 0, false);
      *(ushort_t*)(lds + gb + G_BUFA + woffA[r]) = (ushort_t)pA;
      *(ushort_t*)(lds + gb + G_BUFA + woffB[r]) = (ushort_t)pB;
    }
  };

  auto L2 = [&]() {
    f32x4 acc[4];
    #pragma unroll
    for (int n = 0; n < 4; ++n) acc[n] = (f32x4){b2s[n], b2s[n], b2s[n], b2s[n]};
    __builtin_amdgcn_s_setprio(1);
    #pragma unroll
    for (int c = 0; c < 8; ++c) {
      f8x8 a = *(const f8x8*)(lds + gb + G_BUFA + roff[c]);
      #pragma unroll
      for (int n = 0; n < 4; ++n)
        acc[n] = __builtin_amdgcn_mfma_f32_16x16x32_fp8_fp8(a, w2f[c][n], acc[n], 0, 0, 0);
    }
    __builtin_amdgcn_s_setprio(0);
    #pragma unroll
    for (int r = 0; r < 4; ++r) {
      unsigned pA = (unsigned)__builtin_amdgcn_cvt_pk_fp8_f32(
          tanh_s(acc[0][r]), tanh_s(acc[1][r]), 0, false);
      unsigned pB = (unsigned)__builtin_amdgcn_cvt_pk_fp8_f32(
          tanh_s(acc[2][r]), tanh_s(acc[3][r]), 0, false);
      *(ushort_t*)(lds + gb + G_BUFB + woffA[r]) = (ushort_t)pA;
      *(ushort_t*)(lds + gb + G_BUFB + woffB[r]) = (ushort_t)pB;
    }
  };

  auto L3L4 = [&]() {
    f32x4 acc[4];
    #pragma unroll
    for (int n = 0; n < 4; ++n) acc[n] = (f32x4){b3s[n], b3s[n], b3s[n], b3s[n]};
    __builtin_amdgcn_s_setprio(1);
    #pragma unroll
    for (int c = 0; c < 8; ++c) {
      f8x8 a = *(const f8x8*)(lds + gb + G_BUFB + roff[c]);
      #pragma unroll
      for (int n = 0; n < 4; ++n)
        acc[n] = __builtin_amdgcn_mfma_f32_16x16x32_fp8_fp8(a, w3f[c][n], acc[n], 0, 0, 0);
    }
    __builtin_amdgcn_s_setprio(0);
    #pragma unroll
    for (int r = 0; r < 4; ++r) {
      unsigned pA = (unsigned)__builtin_amdgcn_cvt_pk_fp8_f32(
          tanh_s(acc[0][r]), tanh_s(acc[1][r]), 0, false);
      unsigned pB = (unsigned)__builtin_amdgcn_cvt_pk_fp8_f32(
          tanh_s(acc[2][r]), tanh_s(acc[3][r]), 0, false);
      *(ushort_t*)(lds + gb + G_BUFA + woffA[r]) = (ushort_t)pA;
      *(ushort_t*)(lds + gb + G_BUFA + woffB[r]) = (ushort_t)pB;
    }
    // L4 fused: wave's K-segs {2lw, 2lw+1} are exactly what it just wrote
    asm volatile("s_waitcnt lgkmcnt(0)" ::: "memory");
    __builtin_amdgcn_sched_barrier(0);
    f8x8 a0 = *(const f8x8*)(lds + gb + G_BUFA + roff[0]);
    f8x8 a1 = *(const f8x8*)(lds + gb + G_BUFA + roff[1]);
    f32x4 p4 = __builtin_amdgcn_mfma_f32_16x16x32_fp8_fp8(a0, w4f[0], z4, 0, 0, 0);
    p4 = __builtin_amdgcn_mfma_f32_16x16x32_fp8_fp8(a1, w4f[1], p4, 0, 0, 0);
    #pragma unroll
    for (int r = 0; r < 4; ++r)
      *(float*)(lds + gb + pwoff[r]) = p4[r];
  };

  auto RED = [&](int ev) {
    f32x4 va = *(const f32x4*)(lds + gb + G_PART + ((rs * 64 + cs * 4) << 2));
    float s = ((va[0] + va[1]) + (va[2] + va[3])) + b4v;
    if (rs < 8 && cs < 12) {
      int byt = rs * 64 + ((cs * 4) ^ ((rs & 3) << 4));
      if (ev == 0) {
        zir = zr + DT * s;
        *(ushort_t*)(lds + gb + G_AIN + byt) = f2bf(zir);   // MLP#2 input
      } else {
        float yi = yr + DT * s;
        zr = PP * zir + (1.f - PP) * yi;
        yr = PP * yi + (1.f - PP) * zr;
        *(ushort_t*)(lds + gb + G_AIN + byt) = f2bf(yr);    // next MLP#1 input
      }
    }
  };

  // ---- phase loop: group B trails by 2 phases (82 barriers total) ----
  #pragma unroll 1
  for (int p = 0; p < 20 * 4 + 2; ++p) {
    int ph = p - 2 * grp;
    if (ph >= 0 && ph < 80) {
      int e = ph & 3;
      int evi = ph >> 2;          // eval index 0..19
      if (e == 0)      L1(evi >> 1);
      else if (e == 1) L2();
      else if (e == 2) L3L4();
      else             RED(evi & 1);
    }
    __syncthreads();
  }

  // ---- output: action_aug = [z | y] (group rows 0..7) ----
  if (rs < 8 && cs < 12) {
    out[(row0 + rs) * XDIM + cs]      = zr;
    out[(row0 + rs) * XDIM + 12 + cs] = yr;
  }
}

extern "C" void kernel_launch(void* const* d_in, const int* in_sizes, int n_in,
                              void* d_out, int out_size, void* d_ws, size_t ws_size,
                              hipStream_t stream) {
  const float* obs = (const float*)d_in[0];
  const float* x0  = (const float*)d_in[1];
  const float* W1  = (const float*)d_in[2];
  const float* b1  = (const float*)d_in[3];
  const float* W2  = (const float*)d_in[4];
  const float* b2  = (const float*)d_in[5];
  const float* W3  = (const float*)d_in[6];
  const float* b3  = (const float*)d_in[7];
  const float* W4  = (const float*)d_in[8];
  const float* b4  = (const float*)d_in[9];
  const int*   jac = (const int*)d_in[10];
  float* out = (float*)d_out;
  unsigned char* ws = (unsigned char*)d_ws;

  prep_kernel<<<FRAG_BLOCKS + LP_BLOCKS, 256, 0, stream>>>(W1, b1, W2, W3, W4, x0, jac, out, ws);
  flow_main<<<128, 512, 0, stream>>>(obs, x0, W1, b2, b3, b4, ws, out);
}

// Round 17
// 45.410 us; speedup vs baseline: 1.7635x; 1.7635x over previous
//
#include <hip/hip_runtime.h>
#include <hip/hip_bf16.h>

// Flow_6081673691683: Heun flow (10 steps x 2 MLP evals, H=256) + analytic logdet.
// logabsdet = 240*ln(0.95) exactly -> jacrev/slogdet eliminated.
// R17 = FINAL: revert to R15/R12 (best verified: 45.7us, absmax 0.035).
// Structural-floor evidence (each lever measured >=2 ways):
//  - occupancy: R8/R13 (reg-capped -> spill), R14 (uncapped -> >128/wave, no
//    co-residency); 2 waves/SIMD is the ceiling for this working set
//  - ILP: R10 (same-phase tiles, lockstep, 1.62x worse), R16 (phase-offset
//    groups, 2x per-wave work, 1.75x worse)
//  - LDS: fp8 halving + floor swizzles (R11/R12, conflicts 2.74M->1.02M)
//  - VALU: scaled-tanh/cvt_pk/cinit folding (R6, VALU 37->14%)
//  - scheduling: kt-stagger + setprio + split chains (R9, -0.7us)
// Remaining wall = serial 20-step ODE x 4-phase MLP dependency chain at
// 2 waves/SIMD -- latency-structure, not a pipe roofline.

typedef unsigned short ushort_t;
typedef float f32x4 __attribute__((ext_vector_type(4)));
typedef short s16x8 __attribute__((ext_vector_type(8)));
typedef long f8x8;   // 8 packed fp8 (2 VGPR)

#define NB      2048
#define OBS_D   48
#define XDIM    24
#define NSTEPS  10
#define DT      0.1f
#define PP      0.95f
#define SCL     2.885390081777927f   // 2*log2(e)

// d_ws layout (BYTES)
#define W1U  0        // W1 full bf16 frags (cinit only): 32768 B
#define W1AU 32768    // W1 act-only bf16 frags (k<12, K=32): 16384 B
#define W2F  49152    // W2 fp8 frags: 65536 B
#define W3F  114688   // W3 fp8 frags: 65536 B
#define W4F  180224   // W4 fp8 frags: 4096 B
#define FRAG_BLOCKS 624   // 624*256 == 159744 elements (mixed width)
#define LP_BLOCKS 8

// LDS layout (bytes)
#define LDS_BUFA 0        // 4096 (h1/h3 fp8: 16 rows x 256B, XOR full-ar key)
#define LDS_BUFB 4096     // 4096 (h2 fp8)
#define LDS_AIN  8192     // 1024 (16 rows x 64B bf16 act, XOR (r&3)<<4)
#define LDS_PART 9216     // 8192 (16 row x 16 col x 8 slot f32, slot/bit4 XORs)
#define LDS_STG  17408    // 2048 (init staging bf16: 16 rows x 128B, XOR (r&7)<<4)
#define LDS_TOTAL 19456

__device__ __forceinline__ ushort_t f2bf(float f) {
  unsigned u = __builtin_bit_cast(unsigned, f);
  u += 0x7fffu + ((u >> 16) & 1u);          // RNE
  return (ushort_t)(u >> 16);
}

__device__ __forceinline__ unsigned char f2fp8(float f) {
  int p = __builtin_amdgcn_cvt_pk_fp8_f32(f, 0.f, 0, false);
  return (unsigned char)(p & 0xFF);
}

// input pre-scaled by 2*log2(e):  tanh = 1 - 2/(1 + exp2(u))
__device__ __forceinline__ float tanh_s(float u) {
  float e = __builtin_amdgcn_exp2f(u);
  return __builtin_fmaf(-2.f, __builtin_amdgcn_rcpf(1.f + e), 1.f);
}

// packed-pair byte offset within a 128B bf16 row (cols 0..63), pre-swizzle
__device__ __forceinline__ int pair_byte(int c) {
  return (((c >> 5) << 6) | ((c & 15) << 2) | (((c >> 4) & 1) << 1));
}

// ---------------------------------------------------------------------------
// Prep: weights -> MFMA B-fragment order (permuted K) + analytic log_probs.
// k_eff = kt*32 + 4*(l>>4) + (j>>1) + 16*(j&1)  (identical formula for bf16
// and fp8 pair packing). W1/W2/W3 scaled by 2*log2(e); W4 unscaled (fp8).
// ---------------------------------------------------------------------------
__global__ void prep_kernel(const float* __restrict__ W1, const float* __restrict__ b1,
                            const float* __restrict__ W2, const float* __restrict__ W3,
                            const float* __restrict__ W4, const float* __restrict__ x0,
                            const int* __restrict__ jac, float* __restrict__ out,
                            unsigned char* __restrict__ ws) {
  int bid = blockIdx.x;
  int tid = threadIdx.x;
  if (bid < FRAG_BLOCKS) {
    int e = bid * 256 + tid;           // 0 .. 159743
    if (e < 16384) {                   // W1 full bf16 (61x256 + b1 row 61), scaled
      int kt = e >> 13; int r = e & 8191;
      int nt = r >> 9, l = (r >> 3) & 63, j = r & 7;
      int k = kt * 32 + ((l >> 4) << 2) + (j >> 1) + ((j & 1) << 4);
      int col = nt * 16 + (l & 15);
      float v = SCL * ((k < 61) ? W1[k * 256 + col] : ((k == 61) ? b1[col] : 0.f));
      *(ushort_t*)(ws + W1U + 2 * e) = f2bf(v);
    } else if (e < 24576) {            // W1A bf16: act rows only (k<12), K=32, scaled
      int e2 = e - 16384;
      int nt = e2 >> 9; int r = e2 & 511;
      int l = (r >> 3) & 63, j = r & 7;
      int k = ((l >> 4) << 2) + (j >> 1) + ((j & 1) << 4);
      float v = (k < 12) ? SCL * W1[k * 256 + nt * 16 + (l & 15)] : 0.f;
      *(ushort_t*)(ws + W1AU + 2 * e2) = f2bf(v);
    } else if (e < 90112) {            // W2 fp8, scaled
      int e2 = e - 24576;
      int kt = e2 >> 13; int r = e2 & 8191;
      int nt = r >> 9, l = (r >> 3) & 63, j = r & 7;
      int k = kt * 32 + ((l >> 4) << 2) + (j >> 1) + ((j & 1) << 4);
      ws[W2F + e2] = f2fp8(SCL * W2[k * 256 + nt * 16 + (l & 15)]);
    } else if (e < 155648) {           // W3 fp8, scaled
      int e2 = e - 90112;
      int kt = e2 >> 13; int r = e2 & 8191;
      int nt = r >> 9, l = (r >> 3) & 63, j = r & 7;
      int k = kt * 32 + ((l >> 4) << 2) + (j >> 1) + ((j & 1) << 4);
      ws[W3F + e2] = f2fp8(SCL * W3[k * 256 + nt * 16 + (l & 15)]);
    } else {                           // W4 fp8 (256x12 -> N pad 16), UNscaled
      int e2 = e - 155648;
      int kt = e2 >> 9; int r = e2 & 511;
      int l = (r >> 3) & 63, j = r & 7;
      int k = kt * 32 + ((l >> 4) << 2) + (j >> 1) + ((j & 1) << 4);
      int col = l & 15;
      ws[W4F + e2] = f2fp8((col < 12) ? W4[k * 12 + col] : 0.f);
    }
  } else {
    int s = (bid - FRAG_BLOCKS) * 256 + tid;   // 0..2047
    float acc = 0.f;
    #pragma unroll 4
    for (int j = 0; j < XDIM; ++j) { float v = x0[s * XDIM + j]; acc += v * v; }
    // -0.5*d*ln(2pi) = -22.054524796912143 ; -240*ln(0.95) = +12.310390653012128
    float C = (jac[0] != 0) ? -9.744134143900015f : -22.054524796912143f;
    out[NB * XDIM + s] = -0.5f * acc + C;
  }
}

// ---------------------------------------------------------------------------
// Main: 128 blocks x 512 threads (8 waves), 16 samples/block.
// ---------------------------------------------------------------------------
__global__ __launch_bounds__(512, 2) void flow_main(
    const float* __restrict__ obs, const float* __restrict__ x0,
    const float* __restrict__ W1g, const float* __restrict__ b2g,
    const float* __restrict__ b3g, const float* __restrict__ b4g,
    const unsigned char* __restrict__ ws, float* __restrict__ out) {
  __shared__ char lds[LDS_TOTAL];
  const int tid  = threadIdx.x;
  const int lane = tid & 63;
  const int wv   = tid >> 6;
  const int g    = lane >> 4;
  const int ar   = lane & 15;
  const int row0 = blockIdx.x * 16;
  const int sw   = (ar & 7) << 4;             // bf16 swizzle (STG)
  const int rs   = tid >> 4, cs = tid & 15;   // reduce role (tid<256)

  // staggered fp8 read offsets, FULL-ar key: roff[c] reads seg kt=(wv+c)&7 (b64)
  int roff[8];
  #pragma unroll
  for (int c = 0; c < 8; ++c)
    roff[c] = ar * 256 + (((((wv + c) & 7) * 32) + g * 8) ^ (ar << 3));
  // h-write (fp8 pair, b16, full-row key) + PART-write offsets (slot+bit4 XOR)
  int woff[4], pwoff[4];
  #pragma unroll
  for (int r = 0; r < 4; ++r) {
    int rw = 4 * g + r;
    woff[r]  = rw * 256 + ((wv * 32 + ar * 2) ^ (rw << 3));
    int slot = (wv ^ (g << 1)) ^ ((ar >> 2) & 3);
    pwoff[r] = LDS_PART + ((rw * 128 + ((ar * 8 + slot) ^ ((rw & 1) << 4))) << 2);
  }

  // --- zero STG (512 dw) and AIN (256 dw) ---
  ((unsigned*)(lds + LDS_STG))[tid & 511] = 0u;
  if (tid < 256) ((unsigned*)(lds + LDS_AIN))[tid] = 0u;
  __syncthreads();

  // --- fill STG = [0(act)|obs|0(t)|1(bias)] for the cinit MFMA (bf16) ---
  for (int idx = tid; idx < 16 * OBS_D; idx += 512) {
    int r = idx / OBS_D, o = idx - r * OBS_D;
    int byt = pair_byte(12 + o) ^ ((r & 7) << 4);
    *(ushort_t*)(lds + LDS_STG + r * 128 + byt) = f2bf(obs[(row0 + r) * OBS_D + o]);
  }
  if (tid < 16)   // col 61 = 1.0 -> b1 (scaled b1 lives in W1 frag row 61)
    *(ushort_t*)(lds + LDS_STG + tid * 128 + (pair_byte(61) ^ ((tid & 7) << 4))) = (ushort_t)0x3F80;

  // --- act seed (y0) into AIN (bf16) + z/y state regs (tid<256 roles) ---
  float zr = 0.f, yr = 0.f, zir = 0.f;
  if (tid < 256 && cs < 12) {
    zr = x0[(row0 + rs) * XDIM + cs];
    yr = x0[(row0 + rs) * XDIM + 12 + cs];
    *(ushort_t*)(lds + LDS_AIN + rs * 64 + ((cs * 4) ^ ((rs & 3) << 4))) = f2bf(yr);
  }

  // --- weight fragments (STAGGERED: index c -> kt=(wv+c)&7) ---
  s16x8 w1o[2][2], w1a[2];
  f8x8 w2f[8][2], w3f[8][2], w4f;
  #pragma unroll
  for (int kt = 0; kt < 2; ++kt)
    #pragma unroll
    for (int n = 0; n < 2; ++n)
      w1o[kt][n] = *(const s16x8*)(ws + W1U + (((kt * 16) + (2 * wv + n)) * 64 + lane) * 16);
  #pragma unroll
  for (int n = 0; n < 2; ++n)
    w1a[n] = *(const s16x8*)(ws + W1AU + ((2 * wv + n) * 64 + lane) * 16);
  #pragma unroll
  for (int c = 0; c < 8; ++c) {
    int kt = (wv + c) & 7;
    #pragma unroll
    for (int n = 0; n < 2; ++n) {
      w2f[c][n] = *(const f8x8*)(ws + W2F + (((kt * 16) + (2 * wv + n)) * 64 + lane) * 8);
      w3f[c][n] = *(const f8x8*)(ws + W3F + (((kt * 16) + (2 * wv + n)) * 64 + lane) * 8);
    }
  }
  w4f = *(const f8x8*)(ws + W4F + (wv * 64 + lane) * 8);   // kt = wv (wave-local)
  asm volatile("" : "+v"(w1a[0]), "+v"(w1a[1]), "+v"(w4f));
  #pragma unroll
  for (int c = 0; c < 8; ++c)
    asm volatile("" : "+v"(w2f[c][0]), "+v"(w2f[c][1]), "+v"(w3f[c][0]), "+v"(w3f[c][1]));

  // t-row of W1 (scaled) + biases (scaled; folded into MFMA C-init)
  const float w1t0 = SCL * W1g[60 * 256 + 32 * wv + ar];
  const float w1t1 = SCL * W1g[60 * 256 + 32 * wv + 16 + ar];
  const float b2s0 = SCL * b2g[32 * wv + ar],      b2s1 = SCL * b2g[32 * wv + 16 + ar];
  const float b3s0 = SCL * b3g[32 * wv + ar],      b3s1 = SCL * b3g[32 * wv + 16 + ar];
  const float b4v  = (cs < 12) ? b4g[cs] : 0.f;

  __syncthreads();

  // --- cinit = ([0|obs|0|1] @ W1s): step-invariant L1 pre-activation (bf16) ---
  const f32x4 z4 = {0.f, 0.f, 0.f, 0.f};
  f32x4 ci0 = z4, ci1 = z4;
  #pragma unroll
  for (int kt = 0; kt < 2; ++kt) {
    s16x8 a = *(const s16x8*)(lds + LDS_STG + ar * 128 + ((kt * 64 + g * 16) ^ sw));
    ci0 = __builtin_amdgcn_mfma_f32_16x16x32_bf16(a, w1o[kt][0], ci0, 0, 0, 0);
    ci1 = __builtin_amdgcn_mfma_f32_16x16x32_bf16(a, w1o[kt][1], ci1, 0, 0, 0);
  }
  // (STG never reused -> no extra barrier)

  for (int i = 0; i < NSTEPS; ++i) {
    const float t = (float)i * DT;
    const float t0 = t * w1t0, t1 = t * w1t1;
    #pragma unroll
    for (int ev = 0; ev < 2; ++ev) {
      // ---- L1 (bf16): act @ W1a + (cinit + t*w1t) ----
      f32x4 acc0 = ci0, acc1 = ci1;
      #pragma unroll
      for (int r = 0; r < 4; ++r) { acc0[r] += t0; acc1[r] += t1; }
      {
        s16x8 a = *(const s16x8*)(lds + LDS_AIN + ar * 64 + ((g * 16) ^ ((ar & 3) << 4)));
        acc0 = __builtin_amdgcn_mfma_f32_16x16x32_bf16(a, w1a[0], acc0, 0, 0, 0);
        acc1 = __builtin_amdgcn_mfma_f32_16x16x32_bf16(a, w1a[1], acc1, 0, 0, 0);
      }
      #pragma unroll
      for (int r = 0; r < 4; ++r) {
        unsigned p = (unsigned)__builtin_amdgcn_cvt_pk_fp8_f32(
            tanh_s(acc0[r]), tanh_s(acc1[r]), 0, false);
        *(ushort_t*)(lds + LDS_BUFA + woff[r]) = (ushort_t)p;   // fp8 pair {c, c+16}
      }
      __syncthreads();

      // ---- L2 (fp8): h1 @ W2 (staggered kt, 4x2-deep chains, bias C-init) ----
      f32x4 c0[4], c1[4];
      c0[0] = (f32x4){b2s0, b2s0, b2s0, b2s0}; c1[0] = (f32x4){b2s1, b2s1, b2s1, b2s1};
      c0[1] = z4; c0[2] = z4; c0[3] = z4; c1[1] = z4; c1[2] = z4; c1[3] = z4;
      __builtin_amdgcn_s_setprio(1);
      #pragma unroll
      for (int c = 0; c < 4; ++c) {
        f8x8 a = *(const f8x8*)(lds + LDS_BUFA + roff[c]);
        f8x8 b = *(const f8x8*)(lds + LDS_BUFA + roff[c + 4]);
        c0[c] = __builtin_amdgcn_mfma_f32_16x16x32_fp8_fp8(a, w2f[c][0], c0[c], 0, 0, 0);
        c1[c] = __builtin_amdgcn_mfma_f32_16x16x32_fp8_fp8(a, w2f[c][1], c1[c], 0, 0, 0);
        c0[c] = __builtin_amdgcn_mfma_f32_16x16x32_fp8_fp8(b, w2f[c + 4][0], c0[c], 0, 0, 0);
        c1[c] = __builtin_amdgcn_mfma_f32_16x16x32_fp8_fp8(b, w2f[c + 4][1], c1[c], 0, 0, 0);
      }
      __builtin_amdgcn_s_setprio(0);
      acc0 = (c0[0] + c0[1]) + (c0[2] + c0[3]);
      acc1 = (c1[0] + c1[1]) + (c1[2] + c1[3]);
      #pragma unroll
      for (int r = 0; r < 4; ++r) {
        unsigned p = (unsigned)__builtin_amdgcn_cvt_pk_fp8_f32(
            tanh_s(acc0[r]), tanh_s(acc1[r]), 0, false);
        *(ushort_t*)(lds + LDS_BUFB + woff[r]) = (ushort_t)p;
      }
      __syncthreads();

      // ---- L3 (fp8): h2 @ W3 ----
      c0[0] = (f32x4){b3s0, b3s0, b3s0, b3s0}; c1[0] = (f32x4){b3s1, b3s1, b3s1, b3s1};
      c0[1] = z4; c0[2] = z4; c0[3] = z4; c1[1] = z4; c1[2] = z4; c1[3] = z4;
      __builtin_amdgcn_s_setprio(1);
      #pragma unroll
      for (int c = 0; c < 4; ++c) {
        f8x8 a = *(const f8x8*)(lds + LDS_BUFB + roff[c]);
        f8x8 b = *(const f8x8*)(lds + LDS_BUFB + roff[c + 4]);
        c0[c] = __builtin_amdgcn_mfma_f32_16x16x32_fp8_fp8(a, w3f[c][0], c0[c], 0, 0, 0);
        c1[c] = __builtin_amdgcn_mfma_f32_16x16x32_fp8_fp8(a, w3f[c][1], c1[c], 0, 0, 0);
        c0[c] = __builtin_amdgcn_mfma_f32_16x16x32_fp8_fp8(b, w3f[c + 4][0], c0[c], 0, 0, 0);
        c1[c] = __builtin_amdgcn_mfma_f32_16x16x32_fp8_fp8(b, w3f[c + 4][1], c1[c], 0, 0, 0);
      }
      __builtin_amdgcn_s_setprio(0);
      acc0 = (c0[0] + c0[1]) + (c0[2] + c0[3]);
      acc1 = (c1[0] + c1[1]) + (c1[2] + c1[3]);
      #pragma unroll
      for (int r = 0; r < 4; ++r) {
        unsigned p = (unsigned)__builtin_amdgcn_cvt_pk_fp8_f32(
            tanh_s(acc0[r]), tanh_s(acc1[r]), 0, false);
        *(ushort_t*)(lds + LDS_BUFA + woff[r]) = (ushort_t)p;
      }

      // ---- L4 fused (NO barrier): wave wv's K-slice == seg wv it just wrote ----
      asm volatile("s_waitcnt lgkmcnt(0)" ::: "memory");
      __builtin_amdgcn_sched_barrier(0);
      {
        f8x8 a = *(const f8x8*)(lds + LDS_BUFA + roff[0]);   // kt = wv
        f32x4 p4 = __builtin_amdgcn_mfma_f32_16x16x32_fp8_fp8(a, w4f, z4, 0, 0, 0);
        #pragma unroll
        for (int r = 0; r < 4; ++r)
          *(float*)(lds + pwoff[r]) = p4[r];
      }
      __syncthreads();

      // ---- reduce + Heun (tid<256: row rs, col cs; bit4 key on read) ----
      if (tid < 256) {
        const char* pb = lds + LDS_PART + ((rs * 128 + ((cs * 8) ^ ((rs & 1) << 4))) << 2);
        f32x4 va = *(const f32x4*)pb;
        f32x4 vb = *(const f32x4*)(pb + 16);
        f32x4 sv = va + vb;
        float s = ((sv[0] + sv[1]) + (sv[2] + sv[3])) + b4v;
        if (cs < 12) {
          int byt = rs * 64 + ((cs * 4) ^ ((rs & 3) << 4));
          if (ev == 0) {
            zir = zr + DT * s;
            *(ushort_t*)(lds + LDS_AIN + byt) = f2bf(zir);   // MLP#2 input
          } else {
            float yi = yr + DT * s;
            zr = PP * zir + (1.f - PP) * yi;
            yr = PP * yi + (1.f - PP) * zr;
            *(ushort_t*)(lds + LDS_AIN + byt) = f2bf(yr);    // next MLP#1 input
          }
        }
      }
      __syncthreads();
    }
  }

  // ---- output: action_aug = [z | y] ----
  if (tid < 256 && cs < 12) {
    out[(row0 + rs) * XDIM + cs]      = zr;
    out[(row0 + rs) * XDIM + 12 + cs] = yr;
  }
}

extern "C" void kernel_launch(void* const* d_in, const int* in_sizes, int n_in,
                              void* d_out, int out_size, void* d_ws, size_t ws_size,
                              hipStream_t stream) {
  const float* obs = (const float*)d_in[0];
  const float* x0  = (const float*)d_in[1];
  const float* W1  = (const float*)d_in[2];
  const float* b1  = (const float*)d_in[3];
  const float* W2  = (const float*)d_in[4];
  const float* b2  = (const float*)d_in[5];
  const float* W3  = (const float*)d_in[6];
  const float* b3  = (const float*)d_in[7];
  const float* W4  = (const float*)d_in[8];
  const float* b4  = (const float*)d_in[9];
  const int*   jac = (const int*)d_in[10];
  float* out = (float*)d_out;
  unsigned char* ws = (unsigned char*)d_ws;

  prep_kernel<<<FRAG_BLOCKS + LP_BLOCKS, 256, 0, stream>>>(W1, b1, W2, W3, W4, x0, jac, out, ws);
  flow_main<<<128, 512, 0, stream>>>(obs, x0, W1, b2, b3, b4, ws, out);
}